// Round 4
// baseline (2176.957 us; speedup 1.0000x reference)
//
#include <hip/hip_runtime.h>
#include <stdint.h>

#define H     1024
#define K2    2048
#define NTOT  5120
#define BATCH 64
#define BM 128
#define BN 128
#define BK 64

typedef unsigned short u16;
typedef __attribute__((ext_vector_type(8))) short short8;
typedef __attribute__((ext_vector_type(4))) float floatx4;

__device__ __forceinline__ float bf2f(u16 u) {
    return __uint_as_float(((uint32_t)u) << 16);
}
__device__ __forceinline__ u16 f2bf(float f) {
    uint32_t u = __float_as_uint(f);
    u += 0x7fffu + ((u >> 16) & 1u);
    return (u16)(u >> 16);
}
__device__ __forceinline__ uint32_t pk2(float lo, float hi) {
    return (uint32_t)f2bf(lo) | ((uint32_t)f2bf(hi) << 16);
}
__device__ __forceinline__ float sigf(float x) {
    return 1.0f / (1.0f + __expf(-x));
}
__device__ __forceinline__ float tanh_(float x) {
    float e = __expf(-2.0f * fabsf(x));
    float r = (1.0f - e) / (1.0f + e);
    return copysignf(r, x);
}
// read one logical float element from a maybe-fp32/maybe-bf16 array
__device__ __forceinline__ float rdf(const void* p, long i, bool f32) {
    return f32 ? ((const float*)p)[i] : bf2f(((const u16*)p)[i]);
}

// ---- dtype detector: fp32 memory read as u16 has wild bf16 exponents ----
__global__ void detect_dtype(const u16* __restrict__ emb, int* __restrict__ flag) {
    int lane = threadIdx.x;          // 64 threads
    int cnt = 0;
    for (int i = 0; i < 128; ++i) {
        u16 v = emb[i * 64 + lane];
        int e = (v >> 7) & 0xFF;     // bf16 exponent field
        cnt += (e > 0x85);           // |x| > 64 — impossible for emb data
    }
    for (int off = 32; off; off >>= 1) cnt += __shfl_down(cnt, off, 64);
    if (lane == 0) *flag = (cnt > 256) ? 1 : 0;
}

// ---- pack weights -> canonical bf16 WT[n][k] ----
__global__ void pack_weights(const void* __restrict__ Wio, const void* __restrict__ Uio,
                             const void* __restrict__ Wfl, const void* __restrict__ Ufl,
                             const void* __restrict__ Wfr, const void* __restrict__ Ufr,
                             u16* __restrict__ WT, const int* __restrict__ flagp) {
    bool f32 = (*flagp != 0);
    __shared__ u16 tile[32][33];
    int k0 = blockIdx.x * 32;
    int n0 = blockIdx.y * 32;
    const void *Wp, *Up; int ncols, nloc;
    if (n0 < 3072)      { Wp = Wio; Up = Uio; ncols = 3072; nloc = n0; }
    else if (n0 < 4096) { Wp = Wfl; Up = Ufl; ncols = 1024; nloc = n0 - 3072; }
    else                { Wp = Wfr; Up = Ufr; ncols = 1024; nloc = n0 - 4096; }
    int t = threadIdx.x;
    int c = t & 31, r = t >> 5;
#pragma unroll
    for (int i = 0; i < 4; ++i) {
        int rr = r + i * 8;
        int k = k0 + rr;
        const void* P = (k < 1024) ? Wp : Up;
        long idx = (long)((k < 1024) ? k : k - 1024) * ncols + nloc + c;
        float v = rdf(P, idx, f32);
        tile[rr][c] = f2bf(v);
    }
    __syncthreads();
#pragma unroll
    for (int i = 0; i < 4; ++i) {
        int rr = r + i * 8;
        WT[(long)(n0 + rr) * K2 + k0 + c] = tile[c][rr];
    }
}

// ---- GEMM: G[j][n] = sum_k A[row(j)][k] * WT[n][k]  (VGPR staging) ----
__global__ void gemm_bt(const void* __restrict__ Abase, const int* __restrict__ tokens,
                        const void* __restrict__ emb,
                        long bstride, int aoff, int lp,
                        const u16* __restrict__ BT, float* __restrict__ G,
                        int row0, int m_chunk, const int* __restrict__ flagp) {
    bool f32 = (*flagp != 0);
    long esz = f32 ? 4 : 2;
    __shared__ __align__(16) u16 As[BM * BK];
    __shared__ __align__(16) u16 Bs[BN * BK];
    int tid  = threadIdx.x;
    int lane = tid & 63;
    int w    = tid >> 6;
    int wm   = w >> 1, wn = w & 1;
    int rowTile = blockIdx.x * BM;
    int n0      = blockIdx.y * BN;
    int pmask   = (1 << lp) - 1;

    int lr = tid >> 3;          // 0..31
    int lc = (tid & 7) * 8;     // element col offset

    const char* a0[4];
    const char* a1[4];
    const u16* bsrc[4];
#pragma unroll
    for (int i = 0; i < 4; ++i) {
        int r = i * 32 + lr;
        int j = rowTile + r; if (j >= m_chunk) j = m_chunk - 1;
        int J = row0 + j;
        int b = J >> lp, p = J & pmask;
        const char *p0, *p1;
        if (tokens) {
            p0 = (const char*)emb + (long)tokens[b * 256 + 2 * p] * H * esz;
            p1 = (const char*)emb + (long)tokens[b * 256 + 2 * p + 1] * H * esz;
        } else {
            p0 = (const char*)Abase + ((long)b * bstride + (long)(aoff + 2 * p) * H) * esz;
            p1 = p0 + H * esz;
        }
        a0[i] = p0 + (long)lc * esz;
        a1[i] = p1 + (long)lc * esz;
        int n = n0 + i * 32 + lr;
        bsrc[i] = BT + (long)n * K2 + lc;
    }

    floatx4 acc[4][4];
#pragma unroll
    for (int mt = 0; mt < 4; ++mt)
#pragma unroll
        for (int nt = 0; nt < 4; ++nt)
            acc[mt][nt] = (floatx4){0.f, 0.f, 0.f, 0.f};

    for (int k0 = 0; k0 < K2; k0 += BK) {
        uint4 av[4], bv[4];
#pragma unroll
        for (int i = 0; i < 4; ++i) {
            const char* s = (k0 < H) ? (a0[i] + (long)k0 * esz)
                                     : (a1[i] + (long)(k0 - H) * esz);
            if (f32) {
                uint4 u0 = *(const uint4*)s;
                uint4 u1 = *(const uint4*)(s + 16);
                const float* f0 = (const float*)&u0;
                const float* f1 = (const float*)&u1;
                av[i].x = pk2(f0[0], f0[1]);
                av[i].y = pk2(f0[2], f0[3]);
                av[i].z = pk2(f1[0], f1[1]);
                av[i].w = pk2(f1[2], f1[3]);
            } else {
                av[i] = *(const uint4*)s;
            }
            bv[i] = *(const uint4*)(bsrc[i] + k0);
        }
        __syncthreads();
#pragma unroll
        for (int i = 0; i < 4; ++i) {
            *(uint4*)&As[(i * 32 + lr) * BK + lc] = av[i];
            *(uint4*)&Bs[(i * 32 + lr) * BK + lc] = bv[i];
        }
        __syncthreads();

#pragma unroll
        for (int kb = 0; kb < 2; ++kb) {
            int kfo = kb * 32 + (lane >> 4) * 8;
            short8 af[4], bfv[4];
#pragma unroll
            for (int mt = 0; mt < 4; ++mt)
                af[mt] = *(const short8*)&As[(wm * 64 + mt * 16 + (lane & 15)) * BK + kfo];
#pragma unroll
            for (int nt = 0; nt < 4; ++nt)
                bfv[nt] = *(const short8*)&Bs[(wn * 64 + nt * 16 + (lane & 15)) * BK + kfo];
#pragma unroll
            for (int mt = 0; mt < 4; ++mt)
#pragma unroll
                for (int nt = 0; nt < 4; ++nt)
                    acc[mt][nt] = __builtin_amdgcn_mfma_f32_16x16x32_bf16(
                        af[mt], bfv[nt], acc[mt][nt], 0, 0, 0);
        }
    }

    // epilogue: C/D layout col=lane&15, row=(lane>>4)*4+reg
#pragma unroll
    for (int mt = 0; mt < 4; ++mt) {
#pragma unroll
        for (int r = 0; r < 4; ++r) {
            int row = wm * 64 + mt * 16 + (lane >> 4) * 4 + r;
            int j = rowTile + row;
            if (j < m_chunk) {
                int col = n0 + wn * 64 + (lane & 15);
                float* gp = &G[(long)j * NTOT + col];
#pragma unroll
                for (int nt = 0; nt < 4; ++nt)
                    gp[nt * 16] = acc[mt][nt][r];
            }
        }
    }
}

// ---- gates ----
__global__ void gates(const float* __restrict__ G, const void* __restrict__ bio,
                      const void* __restrict__ bfl, const void* __restrict__ bfr,
                      const void* __restrict__ c_in, void* __restrict__ c_out, int c_bf16,
                      void* __restrict__ out, int lp, int n_in_lvl, int level_off,
                      int row0, int m_chunk, const int* __restrict__ flagp) {
    bool f32 = (*flagp != 0);
    int idx = blockIdx.x * 256 + threadIdx.x;
    int j = idx >> 10;
    if (j >= m_chunk) return;
    int d = idx & 1023;
    int J = row0 + j;
    int b = J >> lp, p = J & ((1 << lp) - 1);
    long gb = (long)j * NTOT + d;
    float gi = G[gb]        + rdf(bio, d, f32);
    float go = G[gb + 1024] + rdf(bio, 1024 + d, f32);
    float gc = G[gb + 2048] + rdf(bio, 2048 + d, f32);
    float gl = G[gb + 3072] + rdf(bfl, d, f32);
    float gr = G[gb + 4096] + rdf(bfr, d, f32);
    float c = sigf(gi) * tanh_(gc);
    if (c_in) {
        long cb = ((long)b * n_in_lvl + 2 * p) * H + d;
        float cl, cr;
        if (c_bf16) { cl = bf2f(((const u16*)c_in)[cb]); cr = bf2f(((const u16*)c_in)[cb + H]); }
        else        { cl = ((const float*)c_in)[cb];     cr = ((const float*)c_in)[cb + H]; }
        c += sigf(gl) * cl + sigf(gr) * cr;
    }
    float h = sigf(go) * tanh_(c);
    long co = (long)J * H + d;
    if (c_bf16) ((u16*)c_out)[co] = f2bf(c);
    else        ((float*)c_out)[co] = c;
    long oi = ((long)b * 255 + level_off + p) * H + d;
    if (f32) ((float*)out)[oi] = h;
    else     ((u16*)out)[oi] = f2bf(h);
}

__global__ void root_copy(const void* __restrict__ out, const void* __restrict__ c_root,
                          int c_bf16, long tail0, const int* __restrict__ flagp) {
    bool f32 = (*flagp != 0);
    int idx = blockIdx.x * 256 + threadIdx.x;   // 131072 total
    long oi = tail0 + idx;
    if (idx < 65536) {
        int b = idx >> 10, d = idx & 1023;
        long src = ((long)b * 255 + 254) * H + d;
        if (f32) ((float*)out)[oi] = ((const float*)out)[src];
        else     ((u16*)out)[oi]   = ((const u16*)out)[src];
    } else {
        int i2 = idx - 65536;
        float cr = c_bf16 ? bf2f(((const u16*)c_root)[i2]) : ((const float*)c_root)[i2];
        if (f32) ((float*)out)[oi] = cr;
        else     ((u16*)out)[oi]   = f2bf(cr);
    }
}

extern "C" void kernel_launch(void* const* d_in, const int* in_sizes, int n_in,
                              void* d_out, int out_size, void* d_ws, size_t ws_size,
                              hipStream_t stream) {
    const int* tokens = (const int*)d_in[0];
    const void* emb = d_in[1];
    const void* Wio = d_in[2];
    const void* bio = d_in[3];
    const void* Uio = d_in[4];
    const void* Wfl = d_in[5];
    const void* bfl = d_in[6];
    const void* Ufl = d_in[7];
    const void* Wfr = d_in[8];
    const void* bfr = d_in[9];
    const void* Ufr = d_in[10];

    // ---- ws carve (all sizes clamped to ws_size; worst case G overlaps c:
    //      finite-wrong but never OOB — keeps failure signatures diagnostic) ----
    char* ws = (char*)d_ws;
    size_t off = 64;
    int* flag = (int*)ws;
    u16* WT = (u16*)(ws + off); off += (size_t)NTOT * K2 * 2;          // 20.97 MB
    size_t cAn = (size_t)BATCH * 128 * H;
    size_t cBn = (size_t)BATCH * 64 * H;
    int c_bf16 = (ws_size >= off + (cAn + cBn) * 4 + (size_t)512 * NTOT * 4) ? 0 : 1;
    size_t csz = c_bf16 ? 2 : 4;
    void* cA = (void*)(ws + off); off += cAn * csz;
    void* cB = (void*)(ws + off); off += cBn * csz;
    size_t avail = (ws_size > off) ? (ws_size - off) : 0;
    long Grows = (long)(avail / ((size_t)NTOT * 4));
    if (Grows > 2048) Grows = 2048;
    if (Grows >= 128) Grows &= ~127L;
    else if (Grows >= 32) Grows &= ~31L;
    else Grows = 32;
    float* G = (float*)(ws + off);
    if (off + (size_t)Grows * NTOT * 4 > ws_size &&
        ws_size > (size_t)Grows * NTOT * 4 + 64)
        G = (float*)(ws + ws_size - (size_t)Grows * NTOT * 4);  // overlap fallback

    detect_dtype<<<1, 64, 0, stream>>>((const u16*)emb, flag);
    pack_weights<<<dim3(64, 160), 256, 0, stream>>>(Wio, Uio, Wfl, Ufl, Wfr, Ufr, WT, flag);

    const int off_out[8] = {0, 128, 192, 224, 240, 248, 252, 254};
    for (int li = 0; li < 8; ++li) {
        int lp = 7 - li;
        int m = BATCH * (128 >> li);
        const void* Abase; long bstride; int aoff;
        const int* tok = nullptr;
        if (li == 0) { Abase = nullptr; bstride = 0; aoff = 0; tok = tokens; }
        else         { Abase = d_out; bstride = 255 * H; aoff = off_out[li - 1]; }
        const void* c_in = (li == 0) ? nullptr : ((li & 1) ? cA : cB);
        void* c_out = (li & 1) ? cB : cA;
        int n_in_lvl = 256 >> li;
        for (long row0 = 0; row0 < m; row0 += Grows) {
            int mc = (int)((m - row0 > Grows) ? Grows : (m - row0));
            dim3 grid((mc + BM - 1) / BM, NTOT / BN);
            gemm_bt<<<grid, 256, 0, stream>>>(Abase, tok, emb, bstride, aoff, lp,
                                              WT, G, (int)row0, mc, flag);
            int gblocks = (mc * H + 255) / 256;
            gates<<<gblocks, 256, 0, stream>>>(G, bio, bfl, bfr, c_in, c_out, c_bf16,
                                               d_out, lp, n_in_lvl, off_out[li],
                                               (int)row0, mc, flag);
        }
    }
    root_copy<<<512, 256, 0, stream>>>(d_out, cB, c_bf16,
                                       (long)BATCH * 255 * H, flag);
}

// Round 5
// 1271.976 us; speedup vs baseline: 1.7115x; 1.7115x over previous
//
#include <hip/hip_runtime.h>
#include <stdint.h>

#define H     1024
#define K2    2048
#define NTOT  5120
#define BATCH 64
#define BM 128
#define BN 128
#define BK 64

typedef unsigned short u16;
typedef __attribute__((ext_vector_type(8))) short short8;
typedef __attribute__((ext_vector_type(4))) float floatx4;

__device__ __forceinline__ float bf2f(u16 u) {
    return __uint_as_float(((uint32_t)u) << 16);
}
__device__ __forceinline__ u16 f2bf(float f) {
    uint32_t u = __float_as_uint(f);
    u += 0x7fffu + ((u >> 16) & 1u);
    return (u16)(u >> 16);
}
__device__ __forceinline__ uint32_t pk2(float lo, float hi) {
    return (uint32_t)f2bf(lo) | ((uint32_t)f2bf(hi) << 16);
}
__device__ __forceinline__ float sigf(float x) {
    return 1.0f / (1.0f + __expf(-x));
}
__device__ __forceinline__ float tanh_(float x) {
    float e = __expf(-2.0f * fabsf(x));
    float r = (1.0f - e) / (1.0f + e);
    return copysignf(r, x);
}

// ---- pack weights (fp32 in) -> bf16 WT[n][k]; k<1024 from W, else U ----
__global__ void pack_weights(const float* __restrict__ Wio, const float* __restrict__ Uio,
                             const float* __restrict__ Wfl, const float* __restrict__ Ufl,
                             const float* __restrict__ Wfr, const float* __restrict__ Ufr,
                             u16* __restrict__ WT) {
    __shared__ u16 tile[32][33];
    int k0 = blockIdx.x * 32;
    int n0 = blockIdx.y * 32;
    const float *Wp, *Up; int ncols, nloc;
    if (n0 < 3072)      { Wp = Wio; Up = Uio; ncols = 3072; nloc = n0; }
    else if (n0 < 4096) { Wp = Wfl; Up = Ufl; ncols = 1024; nloc = n0 - 3072; }
    else                { Wp = Wfr; Up = Ufr; ncols = 1024; nloc = n0 - 4096; }
    int t = threadIdx.x;
    int c = t & 31, r = t >> 5;
#pragma unroll
    for (int i = 0; i < 4; ++i) {
        int rr = r + i * 8;
        int k = k0 + rr;
        float v = (k < 1024) ? Wp[(long)k * ncols + nloc + c]
                             : Up[(long)(k - 1024) * ncols + nloc + c];
        tile[rr][c] = f2bf(v);
    }
    __syncthreads();
#pragma unroll
    for (int i = 0; i < 4; ++i) {
        int rr = r + i * 8;
        WT[(long)(n0 + rr) * K2 + k0 + c] = tile[c][rr];
    }
}

// ---- leaf gather + fp32->bf16: leaf[node][d] = emb[tokens[node]][d] ----
__global__ void leaf_pack(const int* __restrict__ tokens, const float* __restrict__ emb,
                          u16* __restrict__ leaf) {
    int idx = blockIdx.x * 256 + threadIdx.x;   // 16384 blocks -> 4,194,304 float4
    int node = idx >> 8;
    int d4 = idx & 255;
    int tok = tokens[node];
    float4 v = ((const float4*)emb)[(long)tok * 256 + d4];
    uint2 o; o.x = pk2(v.x, v.y); o.y = pk2(v.z, v.w);
    ((uint2*)leaf)[(long)node * 256 + d4] = o;
}

// ---- GEMM (m97): G[j][n] = sum_k A[j][k]*WT[n][k]; A contiguous M x 2048 bf16 ----
__global__ void gemm_bt(const u16* __restrict__ A, const u16* __restrict__ BT,
                        float* __restrict__ G, int mc) {
    __shared__ __align__(16) u16 AsBs[16896];   // 33,792 B; K-loop: As|Bs, epilogue: epi
    u16* As = AsBs;
    u16* Bs = AsBs + 8192;
    float* epi = (float*)AsBs;                  // 64 x 132 fp32
    int tid  = threadIdx.x;
    int lane = tid & 63;
    int w    = tid >> 6;
    int wm   = w >> 1, wn = w & 1;
    int rowTile = blockIdx.x * BM;
    int n0      = blockIdx.y * BN;

    const u16* asrc[4];
    const u16* bsrc[4];
#pragma unroll
    for (int cc = 0; cc < 4; ++cc) {
        int r = cc * 32 + w * 8 + (lane >> 3);
        int j = rowTile + r; if (j >= mc) j = mc - 1;
        asrc[cc] = A + (long)j * K2 + (lane & 7) * 8;
        bsrc[cc] = BT + (long)(n0 + r) * K2 + (lane & 7) * 8;
    }

    floatx4 acc[4][4];
#pragma unroll
    for (int mt = 0; mt < 4; ++mt)
#pragma unroll
        for (int nt = 0; nt < 4; ++nt)
            acc[mt][nt] = (floatx4){0.f, 0.f, 0.f, 0.f};

    for (int k0 = 0; k0 < K2; k0 += BK) {
#pragma unroll
        for (int cc = 0; cc < 4; ++cc) {
            __builtin_amdgcn_global_load_lds(
                (const __attribute__((address_space(1))) void*)(asrc[cc] + k0),
                (__attribute__((address_space(3))) void*)(As + cc * 2048 + w * 512), 16, 0, 0);
            __builtin_amdgcn_global_load_lds(
                (const __attribute__((address_space(1))) void*)(bsrc[cc] + k0),
                (__attribute__((address_space(3))) void*)(Bs + cc * 2048 + w * 512), 16, 0, 0);
        }
        __syncthreads();
#pragma unroll
        for (int kb = 0; kb < 2; ++kb) {
            int kfo = kb * 32 + (lane >> 4) * 8;
            short8 af[4], bfv[4];
#pragma unroll
            for (int mt = 0; mt < 4; ++mt)
                af[mt] = *(const short8*)&As[(wm * 64 + mt * 16 + (lane & 15)) * BK + kfo];
#pragma unroll
            for (int nt = 0; nt < 4; ++nt)
                bfv[nt] = *(const short8*)&Bs[(wn * 64 + nt * 16 + (lane & 15)) * BK + kfo];
#pragma unroll
            for (int mt = 0; mt < 4; ++mt)
#pragma unroll
                for (int nt = 0; nt < 4; ++nt)
                    acc[mt][nt] = __builtin_amdgcn_mfma_f32_16x16x32_bf16(
                        af[mt], bfv[nt], acc[mt][nt], 0, 0, 0);
        }
        __syncthreads();
    }

    // ---- epilogue: LDS round-trip -> fully coalesced float4 stores ----
    // C/D layout: col = lane&15, row = (lane>>4)*4 + reg
#pragma unroll
    for (int s = 0; s < 2; ++s) {
        if (wm == s) {
#pragma unroll
            for (int mt = 0; mt < 4; ++mt)
#pragma unroll
                for (int r = 0; r < 4; ++r) {
                    int lrow = mt * 16 + (lane >> 4) * 4 + r;
#pragma unroll
                    for (int nt = 0; nt < 4; ++nt)
                        epi[lrow * 132 + wn * 64 + nt * 16 + (lane & 15)] = acc[mt][nt][r];
                }
        }
        __syncthreads();
        int gr0 = rowTile + s * 64;
#pragma unroll
        for (int k = 0; k < 8; ++k) {
            int f4 = tid + k * 256;     // 0..2047 float4 slots = 64 rows x 32
            int row = f4 >> 5, c4 = f4 & 31;
            if (gr0 + row < mc) {
                float4 v = *(const float4*)&epi[row * 132 + c4 * 4];
                *(float4*)&G[(long)(gr0 + row) * NTOT + n0 + c4 * 4] = v;
            }
        }
        __syncthreads();
    }
}

// ---- gates (float4): c = sig(i)tanh(ck)+sig(fl)cl+sig(fr)cr; h = sig(o)tanh(c) ----
// writes h fp32 -> forest output, h bf16 -> hnext (next level's A), c -> c_out.
__global__ void gates(const float* __restrict__ G, const float* __restrict__ bio,
                      const float* __restrict__ bfl, const float* __restrict__ bfr,
                      const void* __restrict__ c_in, void* __restrict__ c_out, int c_bf16,
                      float* __restrict__ outF, u16* __restrict__ hnext,
                      int lp, int level_off, int row0, int mc) {
    int idx = blockIdx.x * 256 + threadIdx.x;
    int j = idx >> 8;
    if (j >= mc) return;
    int d = (idx & 255) * 4;
    int J = row0 + j;
    int b = J >> lp, p = J & ((1 << lp) - 1);
    long gb = (long)j * NTOT;
    float4 gi = *(const float4*)&G[gb + d];
    float4 go = *(const float4*)&G[gb + 1024 + d];
    float4 gc = *(const float4*)&G[gb + 2048 + d];
    float4 gl = *(const float4*)&G[gb + 3072 + d];
    float4 gr = *(const float4*)&G[gb + 4096 + d];
    float4 bi = *(const float4*)&bio[d];
    float4 bo = *(const float4*)&bio[1024 + d];
    float4 bc = *(const float4*)&bio[2048 + d];
    float4 bl = *(const float4*)&bfl[d];
    float4 br = *(const float4*)&bfr[d];
    float clv[4] = {0.f, 0.f, 0.f, 0.f}, crv[4] = {0.f, 0.f, 0.f, 0.f};
    if (c_in) {
        long cb = ((long)b * (2 << lp) + 2 * p) * H + d;
        if (c_bf16) {
            uint2 ul = *(const uint2*)((const u16*)c_in + cb);
            uint2 ur = *(const uint2*)((const u16*)c_in + cb + H);
            clv[0] = bf2f((u16)ul.x); clv[1] = bf2f((u16)(ul.x >> 16));
            clv[2] = bf2f((u16)ul.y); clv[3] = bf2f((u16)(ul.y >> 16));
            crv[0] = bf2f((u16)ur.x); crv[1] = bf2f((u16)(ur.x >> 16));
            crv[2] = bf2f((u16)ur.y); crv[3] = bf2f((u16)(ur.y >> 16));
        } else {
            float4 l4 = *(const float4*)((const float*)c_in + cb);
            float4 r4 = *(const float4*)((const float*)c_in + cb + H);
            clv[0] = l4.x; clv[1] = l4.y; clv[2] = l4.z; clv[3] = l4.w;
            crv[0] = r4.x; crv[1] = r4.y; crv[2] = r4.z; crv[3] = r4.w;
        }
    }
    const float* fgi = (const float*)&gi; const float* fgo = (const float*)&go;
    const float* fgc = (const float*)&gc; const float* fgl = (const float*)&gl;
    const float* fgr = (const float*)&gr;
    const float* fbi = (const float*)&bi; const float* fbo = (const float*)&bo;
    const float* fbc = (const float*)&bc; const float* fbl = (const float*)&bl;
    const float* fbr = (const float*)&br;
    float cv[4], hv[4];
    int has_c = (c_in != nullptr);
#pragma unroll
    for (int q = 0; q < 4; ++q) {
        float c = sigf(fgi[q] + fbi[q]) * tanh_(fgc[q] + fbc[q]);
        if (has_c)
            c += sigf(fgl[q] + fbl[q]) * clv[q] + sigf(fgr[q] + fbr[q]) * crv[q];
        cv[q] = c;
        hv[q] = sigf(fgo[q] + fbo[q]) * tanh_(c);
    }
    long co = (long)J * H + d;
    if (c_bf16) {
        uint2 oc; oc.x = pk2(cv[0], cv[1]); oc.y = pk2(cv[2], cv[3]);
        *(uint2*)((u16*)c_out + co) = oc;
    } else {
        *(float4*)((float*)c_out + co) = make_float4(cv[0], cv[1], cv[2], cv[3]);
    }
    long oi = ((long)b * 255 + level_off + p) * H + d;
    *(float4*)&outF[oi] = make_float4(hv[0], hv[1], hv[2], hv[3]);
    uint2 oh; oh.x = pk2(hv[0], hv[1]); oh.y = pk2(hv[2], hv[3]);
    *(uint2*)(hnext + (long)J * H + d) = oh;
}

__global__ void root_copy(const float* __restrict__ outF, const void* __restrict__ c_root,
                          int c_bf16, float* __restrict__ tail) {
    int idx = blockIdx.x * 256 + threadIdx.x;   // 131072
    if (idx < 65536) {
        int b = idx >> 10, d = idx & 1023;
        tail[idx] = outF[((long)b * 255 + 254) * H + d];
    } else {
        int i2 = idx - 65536;
        tail[idx] = c_bf16 ? bf2f(((const u16*)c_root)[i2]) : ((const float*)c_root)[i2];
    }
}

extern "C" void kernel_launch(void* const* d_in, const int* in_sizes, int n_in,
                              void* d_out, int out_size, void* d_ws, size_t ws_size,
                              hipStream_t stream) {
    const int* tokens = (const int*)d_in[0];
    const float* emb = (const float*)d_in[1];
    const float* Wio = (const float*)d_in[2];
    const float* bio = (const float*)d_in[3];
    const float* Uio = (const float*)d_in[4];
    const float* Wfl = (const float*)d_in[5];
    const float* bfl = (const float*)d_in[6];
    const float* Ufl = (const float*)d_in[7];
    const float* Wfr = (const float*)d_in[8];
    const float* bfr = (const float*)d_in[9];
    const float* Ufr = (const float*)d_in[10];
    float* outF = (float*)d_out;

    // ---- ws carve (adaptive) ----
    char* ws = (char*)d_ws;
    size_t off = 0;
    u16* WT   = (u16*)(ws + off); off += (size_t)NTOT * K2 * 2;        // 20.97 MB
    u16* leaf = (u16*)(ws + off); off += (size_t)BATCH * 256 * H * 2;  // 33.55 MB
    u16* hE   = (u16*)(ws + off); off += (size_t)8192 * H * 2;         // 16.78 MB
    u16* hO   = (u16*)(ws + off); off += (size_t)4096 * H * 2;         //  8.39 MB
    size_t cEf = (size_t)8192 * H, cOf = (size_t)4096 * H;             // elements
    int c_bf16 = (ws_size >= off + (cEf + cOf) * 4 + (size_t)512 * NTOT * 4) ? 0 : 1;
    size_t csz = c_bf16 ? 2 : 4;
    void* cE = (void*)(ws + off); off += cEf * csz;
    void* cO = (void*)(ws + off); off += cOf * csz;
    size_t avail = (ws_size > off) ? (ws_size - off) : 0;
    long Grows = (long)(avail / ((size_t)NTOT * 4));
    if (Grows > 2048) Grows = 2048;
    Grows &= ~127L;
    if (Grows < 128) Grows = 128;
    float* G = (float*)(ws + off);

    pack_weights<<<dim3(64, 160), 256, 0, stream>>>(Wio, Uio, Wfl, Ufl, Wfr, Ufr, WT);
    leaf_pack<<<16384, 256, 0, stream>>>(tokens, emb, leaf);

    const int off_out[8] = {0, 128, 192, 224, 240, 248, 252, 254};
    for (int li = 0; li < 8; ++li) {
        int lp = 7 - li;
        long m = (long)BATCH << lp;
        const u16* Acur = (li == 0) ? leaf : ((li & 1) ? hE : hO);
        u16* hnext = (li & 1) ? hO : hE;
        const void* c_in = (li == 0) ? nullptr : ((li & 1) ? cE : cO);
        void* c_out = (li & 1) ? cO : cE;
        for (long row0 = 0; row0 < m; row0 += Grows) {
            int mc = (int)((m - row0 > Grows) ? Grows : (m - row0));
            dim3 grid((mc + BM - 1) / BM, NTOT / BN);
            gemm_bt<<<grid, 256, 0, stream>>>(Acur + row0 * K2, WT, G, mc);
            gates<<<mc, 256, 0, stream>>>(G, bio, bfl, bfr, c_in, c_out, c_bf16,
                                          outF, hnext, lp, off_out[li], (int)row0, mc);
        }
    }
    root_copy<<<512, 256, 0, stream>>>(outF, cO, c_bf16, outF + (size_t)BATCH * 255 * H);
}